// Round 1
// baseline (1119.302 us; speedup 1.0000x reference)
//
#include <hip/hip_runtime.h>
#include <math.h>

#define D128 128
#define NM_ 1043
#define ND_ 2166
#define EM_ 300000
#define ED_ 600000
#define SPLITS 4

// ---------------------------------------------------------------------------
// CSR build: degree + count histogram
// ---------------------------------------------------------------------------
__global__ void deg_cnt_kernel(const int* __restrict__ edge, const float* __restrict__ w,
                               float* __restrict__ deg, int* __restrict__ cnt, int E) {
    int e = blockIdx.x * blockDim.x + threadIdx.x;
    if (e >= E) return;
    int dst = edge[E + e];
    atomicAdd(&deg[dst], w[e]);
    atomicAdd(&cnt[dst], 1);
}

__global__ void dinv_kernel(const float* __restrict__ deg, float* __restrict__ dinv, int n) {
    int i = blockIdx.x * blockDim.x + threadIdx.x;
    if (i >= n) return;
    float dg = deg[i];
    dinv[i] = dg > 0.f ? 1.0f / sqrtf(dg) : 0.f;
}

// single-block exclusive scan of cnt -> rowptr (n up to 2166)
__global__ void scan_kernel(const int* __restrict__ cnt, int* __restrict__ rowptr, int n) {
    __shared__ int tmp[256];
    __shared__ int carry;
    int tid = threadIdx.x;
    if (tid == 0) { carry = 0; rowptr[0] = 0; }
    __syncthreads();
    for (int base = 0; base < n; base += 256) {
        int i = base + tid;
        int v = (i < n) ? cnt[i] : 0;
        tmp[tid] = v;
        __syncthreads();
        for (int off = 1; off < 256; off <<= 1) {
            int t = (tid >= off) ? tmp[tid - off] : 0;
            __syncthreads();
            tmp[tid] += t;
            __syncthreads();
        }
        if (i < n) rowptr[i + 1] = carry + tmp[tid];
        __syncthreads();
        if (tid == 255) carry += tmp[255];
        __syncthreads();
    }
}

__global__ void fill_kernel(const int* __restrict__ edge, const float* __restrict__ w,
                            const float* __restrict__ dinv, const int* __restrict__ rowptr,
                            int* __restrict__ fill, int* __restrict__ ssrc,
                            float* __restrict__ snrm, int E) {
    int e = blockIdx.x * blockDim.x + threadIdx.x;
    if (e >= E) return;
    int src = edge[e];
    int dst = edge[E + e];
    int pos = rowptr[dst] + atomicAdd(&fill[dst], 1);
    ssrc[pos] = src;
    snrm[pos] = dinv[src] * w[e] * dinv[dst];
}

// ---------------------------------------------------------------------------
// Edge aggregation: one block (128 thr) per (node, split). Pure gathers.
// ---------------------------------------------------------------------------
__global__ __launch_bounds__(128) void agg_kernel(const int* __restrict__ ssrc,
                                                  const float* __restrict__ snrm,
                                                  const int* __restrict__ rowptr,
                                                  const float* __restrict__ h,
                                                  float* __restrict__ partial, int n) {
    const int node = blockIdx.x;
    const int sp = blockIdx.y;
    const int tid = threadIdx.x;
    const int beg = rowptr[node], end = rowptr[node + 1];
    const int len = end - beg;
    int b = beg + (len * sp) / SPLITS;
    int e = beg + (len * (sp + 1)) / SPLITS;
    float a0 = 0.f, a1 = 0.f, a2 = 0.f, a3 = 0.f;
    int i = b;
    for (; i + 4 <= e; i += 4) {
        int s0 = ssrc[i], s1 = ssrc[i + 1], s2 = ssrc[i + 2], s3 = ssrc[i + 3];
        float w0 = snrm[i], w1 = snrm[i + 1], w2 = snrm[i + 2], w3 = snrm[i + 3];
        a0 = fmaf(w0, h[(size_t)s0 * D128 + tid], a0);
        a1 = fmaf(w1, h[(size_t)s1 * D128 + tid], a1);
        a2 = fmaf(w2, h[(size_t)s2 * D128 + tid], a2);
        a3 = fmaf(w3, h[(size_t)s3 * D128 + tid], a3);
    }
    for (; i < e; ++i) a0 = fmaf(snrm[i], h[(size_t)ssrc[i] * D128 + tid], a0);
    partial[((size_t)sp * n + node) * D128 + tid] = (a0 + a1) + (a2 + a3);
}

__global__ void reduce_bias_relu(const float* __restrict__ partial, const float* __restrict__ bias,
                                 float* __restrict__ out, int n) {
    int idx = blockIdx.x * blockDim.x + threadIdx.x;
    if (idx >= n * D128) return;
    float v = 0.f;
#pragma unroll
    for (int s = 0; s < SPLITS; ++s) v += partial[(size_t)s * n * D128 + idx];
    out[idx] = fmaxf(v + bias[idx & (D128 - 1)], 0.f);
}

// ---------------------------------------------------------------------------
// fp32 GEMM: C[M,N] = A[M,K] @ B[N,K]^T (+bias, relu). 64x64 tile, 4x4 micro.
// ---------------------------------------------------------------------------
template <bool BR>
__global__ __launch_bounds__(256) void gemm_tn(const float* __restrict__ A,
                                               const float* __restrict__ B,
                                               const float* __restrict__ bias,
                                               float* __restrict__ C, int M, int N, int K) {
    __shared__ float As[32][68];
    __shared__ float Bs[32][68];
    const int m0 = blockIdx.x * 64;
    const int n0 = blockIdx.y * 64;
    const int tid = threadIdx.x;
    const int tm = tid & 15;
    const int tn = tid >> 4;
    float acc[4][4] = {};
    for (int k0 = 0; k0 < K; k0 += 32) {
#pragma unroll
        for (int f = tid; f < 512; f += 256) {
            int r = f >> 3, kg = (f & 7) << 2;
            int gm = m0 + r;
            if (gm > M - 1) gm = M - 1;
            const float4 v = *reinterpret_cast<const float4*>(A + (size_t)gm * K + k0 + kg);
            As[kg + 0][r] = v.x; As[kg + 1][r] = v.y; As[kg + 2][r] = v.z; As[kg + 3][r] = v.w;
        }
#pragma unroll
        for (int f = tid; f < 512; f += 256) {
            int r = f >> 3, kg = (f & 7) << 2;
            const float4 v = *reinterpret_cast<const float4*>(B + (size_t)(n0 + r) * K + k0 + kg);
            Bs[kg + 0][r] = v.x; Bs[kg + 1][r] = v.y; Bs[kg + 2][r] = v.z; Bs[kg + 3][r] = v.w;
        }
        __syncthreads();
#pragma unroll
        for (int kc = 0; kc < 32; ++kc) {
            float4 a = *reinterpret_cast<const float4*>(&As[kc][tm << 2]);
            float4 b = *reinterpret_cast<const float4*>(&Bs[kc][tn << 2]);
            acc[0][0] = fmaf(a.x, b.x, acc[0][0]); acc[0][1] = fmaf(a.x, b.y, acc[0][1]);
            acc[0][2] = fmaf(a.x, b.z, acc[0][2]); acc[0][3] = fmaf(a.x, b.w, acc[0][3]);
            acc[1][0] = fmaf(a.y, b.x, acc[1][0]); acc[1][1] = fmaf(a.y, b.y, acc[1][1]);
            acc[1][2] = fmaf(a.y, b.z, acc[1][2]); acc[1][3] = fmaf(a.y, b.w, acc[1][3]);
            acc[2][0] = fmaf(a.z, b.x, acc[2][0]); acc[2][1] = fmaf(a.z, b.y, acc[2][1]);
            acc[2][2] = fmaf(a.z, b.z, acc[2][2]); acc[2][3] = fmaf(a.z, b.w, acc[2][3]);
            acc[3][0] = fmaf(a.w, b.x, acc[3][0]); acc[3][1] = fmaf(a.w, b.y, acc[3][1]);
            acc[3][2] = fmaf(a.w, b.z, acc[3][2]); acc[3][3] = fmaf(a.w, b.w, acc[3][3]);
        }
        __syncthreads();
    }
#pragma unroll
    for (int i = 0; i < 4; ++i) {
        int gm = m0 + (tm << 2) + i;
        if (gm < M) {
            float o[4];
#pragma unroll
            for (int j = 0; j < 4; ++j) {
                float v = acc[i][j];
                if (BR) v = fmaxf(v + bias[n0 + (tn << 2) + j], 0.f);
                o[j] = v;
            }
            float4 st = {o[0], o[1], o[2], o[3]};
            *reinterpret_cast<float4*>(C + (size_t)gm * N + n0 + (tn << 2)) = st;
        }
    }
}

// ---------------------------------------------------------------------------
// channel-mean reduction + attention scales
// ---------------------------------------------------------------------------
__global__ __launch_bounds__(256) void sum_kernel(const float* __restrict__ x, int count,
                                                  float* __restrict__ slot) {
    __shared__ float red[256];
    float s = 0.f;
    for (int i = blockIdx.x * 256 + threadIdx.x; i < count; i += gridDim.x * 256) s += x[i];
    red[threadIdx.x] = s;
    __syncthreads();
    for (int off = 128; off > 0; off >>= 1) {
        if (threadIdx.x < off) red[threadIdx.x] += red[threadIdx.x + off];
        __syncthreads();
    }
    if (threadIdx.x == 0) atomicAdd(slot, red[0]);
}

__global__ void att_kernel(const float* __restrict__ sums,
                           const float* __restrict__ mW1, const float* __restrict__ mb1,
                           const float* __restrict__ mW2, const float* __restrict__ mb2,
                           const float* __restrict__ dW1, const float* __restrict__ db1,
                           const float* __restrict__ dW2, const float* __restrict__ db2,
                           float* __restrict__ scales) {
    if (threadIdx.x != 0 || blockIdx.x != 0) return;
    float mean[4], a[4];
    const float invM = 1.0f / (128.f * (float)NM_);
    for (int c = 0; c < 4; ++c) mean[c] = sums[c] * invM;
    for (int i = 0; i < 4; ++i) {
        float v = mb1[i];
        for (int j = 0; j < 4; ++j) v += mW1[i * 4 + j] * mean[j];
        a[i] = fmaxf(v, 0.f);
    }
    for (int c = 0; c < 4; ++c) {
        float v = mb2[c];
        for (int j = 0; j < 4; ++j) v += mW2[c * 4 + j] * a[j];
        scales[c] = 1.f / (1.f + expf(-v));
    }
    const float invD = 1.0f / (128.f * (float)ND_);
    float md[2] = {(sums[4] + sums[6]) * invD, (sums[5] + sums[7]) * invD};
    float ad[2];
    for (int i = 0; i < 2; ++i) {
        float v = db1[i];
        for (int j = 0; j < 2; ++j) v += dW1[i * 2 + j] * md[j];
        ad[i] = fmaxf(v, 0.f);
    }
    for (int c = 0; c < 2; ++c) {
        float v = db2[c];
        for (int j = 0; j < 2; ++j) v += dW2[c * 2 + j] * ad[j];
        scales[4 + c] = 1.f / (1.f + expf(-v));
    }
}

// ---------------------------------------------------------------------------
// build fusion inputs (scaled channel concat)
// ---------------------------------------------------------------------------
__global__ void cat_m_kernel(const float* __restrict__ c0, const float* __restrict__ c1,
                             const float* __restrict__ c2, const float* __restrict__ c3,
                             const float* __restrict__ scales, float* __restrict__ out) {
    int idx = blockIdx.x * blockDim.x + threadIdx.x;
    if (idx >= NM_ * 512) return;
    int i = idx >> 9;
    int k = idx & 511;
    int c = k >> 7;
    int j = k & 127;
    const float* p = (c == 0) ? c0 : (c == 1) ? c1 : (c == 2) ? c2 : c3;
    out[idx] = fmaxf(scales[c] * p[(size_t)i * D128 + j], 0.f);
}

__global__ void cat_d_kernel(const float* __restrict__ d1a, const float* __restrict__ d1b,
                             const float* __restrict__ d2a, const float* __restrict__ d2b,
                             const float* __restrict__ scales, float* __restrict__ out) {
    int idx = blockIdx.x * blockDim.x + threadIdx.x;
    if (idx >= ND_ * 256) return;
    int i = idx >> 8;
    int k = idx & 255;
    int c = k >> 7;
    int j = k & 127;
    const float* pa = c ? d1b : d1a;
    const float* pb = c ? d2b : d2a;
    out[idx] = fmaxf(scales[4 + c] * (pa[(size_t)i * D128 + j] + pb[(size_t)i * D128 + j]), 0.f);
}

// ---------------------------------------------------------------------------
extern "C" void kernel_launch(void* const* d_in, const int* in_sizes, int n_in,
                              void* d_out, int out_size, void* d_ws, size_t ws_size,
                              hipStream_t stream) {
    const float* mirna_x = (const float*)d_in[0];
    const float* drug_x  = (const float*)d_in[1];
    // view input bases: m1=2, m2=8, d1=14, d2=20
    const float* m_fc1_W = (const float*)d_in[26];
    const float* m_fc1_b = (const float*)d_in[27];
    const float* m_fc2_W = (const float*)d_in[28];
    const float* m_fc2_b = (const float*)d_in[29];
    const float* d_fc1_W = (const float*)d_in[30];
    const float* d_fc1_b = (const float*)d_in[31];
    const float* d_fc2_W = (const float*)d_in[32];
    const float* d_fc2_b = (const float*)d_in[33];
    const float* m_fus_W1 = (const float*)d_in[34];
    const float* m_fus_b1 = (const float*)d_in[35];
    const float* m_fus_W2 = (const float*)d_in[36];
    const float* m_fus_b2 = (const float*)d_in[37];
    const float* d_fus_W1 = (const float*)d_in[38];
    const float* d_fus_b1 = (const float*)d_in[39];
    const float* d_fus_W2 = (const float*)d_in[40];
    const float* d_fus_b2 = (const float*)d_in[41];
    float* out = (float*)d_out;

    // workspace carve-up (~22 MB total)
    char* ws = (char*)d_ws;
    size_t off = 0;
    auto take = [&](size_t bytes) -> void* {
        void* p = ws + off;
        off += (bytes + 255) & ~(size_t)255;
        return p;
    };
    int*   ssrc   = (int*)take((size_t)ED_ * 4);
    float* snrm   = (float*)take((size_t)ED_ * 4);
    float* deg    = (float*)take((size_t)ND_ * 4);
    int*   cnt    = (int*)take((size_t)ND_ * 4);
    int*   rowptr = (int*)take((size_t)(ND_ + 1) * 4);
    int*   fillc  = (int*)take((size_t)ND_ * 4);
    float* dinv   = (float*)take((size_t)ND_ * 4);
    float* hbuf   = (float*)take((size_t)ND_ * D128 * 4);
    float* m1a = (float*)take((size_t)NM_ * D128 * 4);
    float* m1b = (float*)take((size_t)NM_ * D128 * 4);
    float* m2a = (float*)take((size_t)NM_ * D128 * 4);
    float* m2b = (float*)take((size_t)NM_ * D128 * 4);
    float* d1a = (float*)take((size_t)ND_ * D128 * 4);
    float* d1b = (float*)take((size_t)ND_ * D128 * 4);
    float* d2a = (float*)take((size_t)ND_ * D128 * 4);
    float* d2b = (float*)take((size_t)ND_ * D128 * 4);
    float* partial = (float*)take((size_t)SPLITS * ND_ * D128 * 4);
    float* sums   = (float*)take(8 * 4);
    float* scales = (float*)take(8 * 4);
    float* catb   = (float*)take((size_t)ND_ * 256 * 4);  // >= NM_*512
    float* fush1  = (float*)take((size_t)ND_ * 256 * 4);
    (void)ws_size; (void)in_sizes; (void)n_in; (void)out_size;

    auto run_view = [&](const int* edge, const float* w, const float* W1, const float* b1,
                        const float* W2, const float* b2, const float* x, float* out1,
                        float* out2, int n, int E) {
        hipMemsetAsync(deg, 0, (size_t)n * 4, stream);
        hipMemsetAsync(cnt, 0, (size_t)n * 4, stream);
        hipMemsetAsync(fillc, 0, (size_t)n * 4, stream);
        deg_cnt_kernel<<<(E + 255) / 256, 256, 0, stream>>>(edge, w, deg, cnt, E);
        dinv_kernel<<<(n + 255) / 256, 256, 0, stream>>>(deg, dinv, n);
        scan_kernel<<<1, 256, 0, stream>>>(cnt, rowptr, n);
        fill_kernel<<<(E + 255) / 256, 256, 0, stream>>>(edge, w, dinv, rowptr, fillc, ssrc, snrm, E);
        // layer 1
        gemm_tn<false><<<dim3((n + 63) / 64, 2), 256, 0, stream>>>(x, W1, nullptr, hbuf, n, 128, 128);
        agg_kernel<<<dim3(n, SPLITS), 128, 0, stream>>>(ssrc, snrm, rowptr, hbuf, partial, n);
        reduce_bias_relu<<<(n * D128 + 255) / 256, 256, 0, stream>>>(partial, b1, out1, n);
        // layer 2
        gemm_tn<false><<<dim3((n + 63) / 64, 2), 256, 0, stream>>>(out1, W2, nullptr, hbuf, n, 128, 128);
        agg_kernel<<<dim3(n, SPLITS), 128, 0, stream>>>(ssrc, snrm, rowptr, hbuf, partial, n);
        reduce_bias_relu<<<(n * D128 + 255) / 256, 256, 0, stream>>>(partial, b2, out2, n);
    };

    run_view((const int*)d_in[2], (const float*)d_in[3], (const float*)d_in[4],
             (const float*)d_in[5], (const float*)d_in[6], (const float*)d_in[7], mirna_x,
             m1a, m1b, NM_, EM_);
    run_view((const int*)d_in[8], (const float*)d_in[9], (const float*)d_in[10],
             (const float*)d_in[11], (const float*)d_in[12], (const float*)d_in[13], mirna_x,
             m2a, m2b, NM_, EM_);
    run_view((const int*)d_in[14], (const float*)d_in[15], (const float*)d_in[16],
             (const float*)d_in[17], (const float*)d_in[18], (const float*)d_in[19], drug_x,
             d1a, d1b, ND_, ED_);
    run_view((const int*)d_in[20], (const float*)d_in[21], (const float*)d_in[22],
             (const float*)d_in[23], (const float*)d_in[24], (const float*)d_in[25], drug_x,
             d2a, d2b, ND_, ED_);

    // channel sums -> attention scales
    hipMemsetAsync(sums, 0, 8 * 4, stream);
    sum_kernel<<<64, 256, 0, stream>>>(m1a, NM_ * D128, sums + 0);
    sum_kernel<<<64, 256, 0, stream>>>(m1b, NM_ * D128, sums + 1);
    sum_kernel<<<64, 256, 0, stream>>>(m2a, NM_ * D128, sums + 2);
    sum_kernel<<<64, 256, 0, stream>>>(m2b, NM_ * D128, sums + 3);
    sum_kernel<<<64, 256, 0, stream>>>(d1a, ND_ * D128, sums + 4);
    sum_kernel<<<64, 256, 0, stream>>>(d1b, ND_ * D128, sums + 5);
    sum_kernel<<<64, 256, 0, stream>>>(d2a, ND_ * D128, sums + 6);
    sum_kernel<<<64, 256, 0, stream>>>(d2b, ND_ * D128, sums + 7);
    att_kernel<<<1, 64, 0, stream>>>(sums, m_fc1_W, m_fc1_b, m_fc2_W, m_fc2_b,
                                     d_fc1_W, d_fc1_b, d_fc2_W, d_fc2_b, scales);

    // miRNA fusion -> out[0 : NM)
    cat_m_kernel<<<(NM_ * 512 + 255) / 256, 256, 0, stream>>>(m1a, m1b, m2a, m2b, scales, catb);
    gemm_tn<true><<<dim3((NM_ + 63) / 64, 4), 256, 0, stream>>>(catb, m_fus_W1, m_fus_b1, fush1,
                                                                NM_, 256, 512);
    gemm_tn<true><<<dim3((NM_ + 63) / 64, 2), 256, 0, stream>>>(fush1, m_fus_W2, m_fus_b2, out,
                                                                NM_, 128, 256);
    // drug fusion -> out[NM : NM+ND)
    cat_d_kernel<<<(ND_ * 256 + 255) / 256, 256, 0, stream>>>(d1a, d1b, d2a, d2b, scales, catb);
    gemm_tn<true><<<dim3((ND_ + 63) / 64, 4), 256, 0, stream>>>(catb, d_fus_W1, d_fus_b1, fush1,
                                                                ND_, 256, 256);
    gemm_tn<true><<<dim3((ND_ + 63) / 64, 2), 256, 0, stream>>>(fush1, d_fus_W2, d_fus_b2,
                                                                out + (size_t)NM_ * D128, ND_, 128, 256);
}

// Round 2
// 606.665 us; speedup vs baseline: 1.8450x; 1.8450x over previous
//
#include <hip/hip_runtime.h>
#include <math.h>

#define D128 128
#define NM_ 1043
#define ND_ 2166
#define EM_ 300000
#define ED_ 600000
#define SPLITS 4
#define NB 128          // histogram privatization blocks
#define NMAX 2176       // LDS table size (>= ND_)

// ---------------------------------------------------------------------------
// CSR build, pass 1: per-block privatized histograms (LDS atomics only)
// ---------------------------------------------------------------------------
__global__ __launch_bounds__(256) void hist_kernel(const int* __restrict__ edge,
                                                   const float* __restrict__ w,
                                                   int* __restrict__ pcnt,
                                                   float* __restrict__ pdeg, int n, int E) {
    __shared__ int lc[NMAX];
    __shared__ float ld[NMAX];
    for (int i = threadIdx.x; i < n; i += 256) { lc[i] = 0; ld[i] = 0.f; }
    __syncthreads();
    const int per = (E + NB - 1) / NB;
    const int b = blockIdx.x * per;
    const int e = min(E, b + per);
    for (int i = b + threadIdx.x; i < e; i += 256) {
        int dst = edge[E + i];
        atomicAdd(&lc[dst], 1);
        atomicAdd(&ld[dst], w[i]);
    }
    __syncthreads();
    for (int i = threadIdx.x; i < n; i += 256) {
        pcnt[(size_t)blockIdx.x * n + i] = lc[i];
        pdeg[(size_t)blockIdx.x * n + i] = ld[i];
    }
}

// column-reduce partials -> cnt, dinv
__global__ void colred_kernel(const int* __restrict__ pcnt, const float* __restrict__ pdeg,
                              int* __restrict__ cnt, float* __restrict__ dinv, int n) {
    int i = blockIdx.x * blockDim.x + threadIdx.x;
    if (i >= n) return;
    int c = 0;
    float dg = 0.f;
    for (int b = 0; b < NB; ++b) {
        c += pcnt[(size_t)b * n + i];
        dg += pdeg[(size_t)b * n + i];
    }
    cnt[i] = c;
    dinv[i] = dg > 0.f ? 1.0f / sqrtf(dg) : 0.f;
}

// single-block exclusive scan of cnt -> rowptr (n up to 2166)
__global__ void scan_kernel(const int* __restrict__ cnt, int* __restrict__ rowptr, int n) {
    __shared__ int tmp[256];
    __shared__ int carry;
    int tid = threadIdx.x;
    if (tid == 0) { carry = 0; rowptr[0] = 0; }
    __syncthreads();
    for (int base = 0; base < n; base += 256) {
        int i = base + tid;
        int v = (i < n) ? cnt[i] : 0;
        tmp[tid] = v;
        __syncthreads();
        for (int off = 1; off < 256; off <<= 1) {
            int t = (tid >= off) ? tmp[tid - off] : 0;
            __syncthreads();
            tmp[tid] += t;
            __syncthreads();
        }
        if (i < n) rowptr[i + 1] = carry + tmp[tid];
        __syncthreads();
        if (tid == 255) carry += tmp[255];
        __syncthreads();
    }
}

// per-(block,bin) bases: cum[b][i] = rowptr[i] + sum_{b'<b} pcnt[b'][i]
__global__ void cum_kernel(const int* __restrict__ pcnt, const int* __restrict__ rowptr,
                           int* __restrict__ cum, int n) {
    int i = blockIdx.x * blockDim.x + threadIdx.x;
    if (i >= n) return;
    int run = rowptr[i];
    for (int b = 0; b < NB; ++b) {
        cum[(size_t)b * n + i] = run;
        run += pcnt[(size_t)b * n + i];
    }
}

// CSR build, pass 2: place edges using LDS counters seeded with global bases
__global__ __launch_bounds__(256) void fill2_kernel(const int* __restrict__ edge,
                                                    const float* __restrict__ w,
                                                    const float* __restrict__ dinv,
                                                    const int* __restrict__ cum,
                                                    int* __restrict__ ssrc,
                                                    float* __restrict__ snrm, int n, int E) {
    __shared__ int lc[NMAX];
    for (int i = threadIdx.x; i < n; i += 256) lc[i] = cum[(size_t)blockIdx.x * n + i];
    __syncthreads();
    const int per = (E + NB - 1) / NB;
    const int b = blockIdx.x * per;
    const int e = min(E, b + per);
    for (int i = b + threadIdx.x; i < e; i += 256) {
        int src = edge[i];
        int dst = edge[E + i];
        int pos = atomicAdd(&lc[dst], 1);
        ssrc[pos] = src;
        snrm[pos] = dinv[src] * w[i] * dinv[dst];
    }
}

// ---------------------------------------------------------------------------
// Edge aggregation: one block (128 thr) per (node, split). Pure gathers.
// ---------------------------------------------------------------------------
__global__ __launch_bounds__(128) void agg_kernel(const int* __restrict__ ssrc,
                                                  const float* __restrict__ snrm,
                                                  const int* __restrict__ rowptr,
                                                  const float* __restrict__ h,
                                                  float* __restrict__ partial, int n) {
    const int node = blockIdx.x;
    const int sp = blockIdx.y;
    const int tid = threadIdx.x;
    const int beg = rowptr[node], end = rowptr[node + 1];
    const int len = end - beg;
    int b = beg + (len * sp) / SPLITS;
    int e = beg + (len * (sp + 1)) / SPLITS;
    float a0 = 0.f, a1 = 0.f, a2 = 0.f, a3 = 0.f;
    int i = b;
    for (; i + 4 <= e; i += 4) {
        int s0 = ssrc[i], s1 = ssrc[i + 1], s2 = ssrc[i + 2], s3 = ssrc[i + 3];
        float w0 = snrm[i], w1 = snrm[i + 1], w2 = snrm[i + 2], w3 = snrm[i + 3];
        a0 = fmaf(w0, h[(size_t)s0 * D128 + tid], a0);
        a1 = fmaf(w1, h[(size_t)s1 * D128 + tid], a1);
        a2 = fmaf(w2, h[(size_t)s2 * D128 + tid], a2);
        a3 = fmaf(w3, h[(size_t)s3 * D128 + tid], a3);
    }
    for (; i < e; ++i) a0 = fmaf(snrm[i], h[(size_t)ssrc[i] * D128 + tid], a0);
    partial[((size_t)sp * n + node) * D128 + tid] = (a0 + a1) + (a2 + a3);
}

__global__ void reduce_bias_relu(const float* __restrict__ partial, const float* __restrict__ bias,
                                 float* __restrict__ out, int n) {
    int idx = blockIdx.x * blockDim.x + threadIdx.x;
    if (idx >= n * D128) return;
    float v = 0.f;
#pragma unroll
    for (int s = 0; s < SPLITS; ++s) v += partial[(size_t)s * n * D128 + idx];
    out[idx] = fmaxf(v + bias[idx & (D128 - 1)], 0.f);
}

// ---------------------------------------------------------------------------
// fp32 GEMM: C[M,N] = A[M,K] @ B[N,K]^T (+bias, relu). 64x64 tile, 4x4 micro.
// ---------------------------------------------------------------------------
template <bool BR>
__global__ __launch_bounds__(256) void gemm_tn(const float* __restrict__ A,
                                               const float* __restrict__ B,
                                               const float* __restrict__ bias,
                                               float* __restrict__ C, int M, int N, int K) {
    __shared__ float As[32][68];
    __shared__ float Bs[32][68];
    const int m0 = blockIdx.x * 64;
    const int n0 = blockIdx.y * 64;
    const int tid = threadIdx.x;
    const int tm = tid & 15;
    const int tn = tid >> 4;
    float acc[4][4] = {};
    for (int k0 = 0; k0 < K; k0 += 32) {
#pragma unroll
        for (int f = tid; f < 512; f += 256) {
            int r = f >> 3, kg = (f & 7) << 2;
            int gm = m0 + r;
            if (gm > M - 1) gm = M - 1;
            const float4 v = *reinterpret_cast<const float4*>(A + (size_t)gm * K + k0 + kg);
            As[kg + 0][r] = v.x; As[kg + 1][r] = v.y; As[kg + 2][r] = v.z; As[kg + 3][r] = v.w;
        }
#pragma unroll
        for (int f = tid; f < 512; f += 256) {
            int r = f >> 3, kg = (f & 7) << 2;
            const float4 v = *reinterpret_cast<const float4*>(B + (size_t)(n0 + r) * K + k0 + kg);
            Bs[kg + 0][r] = v.x; Bs[kg + 1][r] = v.y; Bs[kg + 2][r] = v.z; Bs[kg + 3][r] = v.w;
        }
        __syncthreads();
#pragma unroll
        for (int kc = 0; kc < 32; ++kc) {
            float4 a = *reinterpret_cast<const float4*>(&As[kc][tm << 2]);
            float4 b = *reinterpret_cast<const float4*>(&Bs[kc][tn << 2]);
            acc[0][0] = fmaf(a.x, b.x, acc[0][0]); acc[0][1] = fmaf(a.x, b.y, acc[0][1]);
            acc[0][2] = fmaf(a.x, b.z, acc[0][2]); acc[0][3] = fmaf(a.x, b.w, acc[0][3]);
            acc[1][0] = fmaf(a.y, b.x, acc[1][0]); acc[1][1] = fmaf(a.y, b.y, acc[1][1]);
            acc[1][2] = fmaf(a.y, b.z, acc[1][2]); acc[1][3] = fmaf(a.y, b.w, acc[1][3]);
            acc[2][0] = fmaf(a.z, b.x, acc[2][0]); acc[2][1] = fmaf(a.z, b.y, acc[2][1]);
            acc[2][2] = fmaf(a.z, b.z, acc[2][2]); acc[2][3] = fmaf(a.z, b.w, acc[2][3]);
            acc[3][0] = fmaf(a.w, b.x, acc[3][0]); acc[3][1] = fmaf(a.w, b.y, acc[3][1]);
            acc[3][2] = fmaf(a.w, b.z, acc[3][2]); acc[3][3] = fmaf(a.w, b.w, acc[3][3]);
        }
        __syncthreads();
    }
#pragma unroll
    for (int i = 0; i < 4; ++i) {
        int gm = m0 + (tm << 2) + i;
        if (gm < M) {
            float o[4];
#pragma unroll
            for (int j = 0; j < 4; ++j) {
                float v = acc[i][j];
                if (BR) v = fmaxf(v + bias[n0 + (tn << 2) + j], 0.f);
                o[j] = v;
            }
            float4 st = {o[0], o[1], o[2], o[3]};
            *reinterpret_cast<float4*>(C + (size_t)gm * N + n0 + (tn << 2)) = st;
        }
    }
}

// ---------------------------------------------------------------------------
// batched channel-mean reduction + attention scales
// ---------------------------------------------------------------------------
struct SumArgs {
    const float* p[8];
    int cnt[8];
};

__global__ __launch_bounds__(256) void sum8_kernel(SumArgs args, float* __restrict__ sums) {
    __shared__ float red[256];
    const int ch = blockIdx.y;
    const float* x = args.p[ch];
    const int count = args.cnt[ch];
    float s = 0.f;
    for (int i = blockIdx.x * 256 + threadIdx.x; i < count; i += gridDim.x * 256) s += x[i];
    red[threadIdx.x] = s;
    __syncthreads();
    for (int off = 128; off > 0; off >>= 1) {
        if (threadIdx.x < off) red[threadIdx.x] += red[threadIdx.x + off];
        __syncthreads();
    }
    if (threadIdx.x == 0) atomicAdd(&sums[ch], red[0]);
}

__global__ void att_kernel(const float* __restrict__ sums,
                           const float* __restrict__ mW1, const float* __restrict__ mb1,
                           const float* __restrict__ mW2, const float* __restrict__ mb2,
                           const float* __restrict__ dW1, const float* __restrict__ db1,
                           const float* __restrict__ dW2, const float* __restrict__ db2,
                           float* __restrict__ scales) {
    if (threadIdx.x != 0 || blockIdx.x != 0) return;
    float mean[4], a[4];
    const float invM = 1.0f / (128.f * (float)NM_);
    for (int c = 0; c < 4; ++c) mean[c] = sums[c] * invM;
    for (int i = 0; i < 4; ++i) {
        float v = mb1[i];
        for (int j = 0; j < 4; ++j) v += mW1[i * 4 + j] * mean[j];
        a[i] = fmaxf(v, 0.f);
    }
    for (int c = 0; c < 4; ++c) {
        float v = mb2[c];
        for (int j = 0; j < 4; ++j) v += mW2[c * 4 + j] * a[j];
        scales[c] = 1.f / (1.f + expf(-v));
    }
    const float invD = 1.0f / (128.f * (float)ND_);
    float md[2] = {(sums[4] + sums[6]) * invD, (sums[5] + sums[7]) * invD};
    float ad[2];
    for (int i = 0; i < 2; ++i) {
        float v = db1[i];
        for (int j = 0; j < 2; ++j) v += dW1[i * 2 + j] * md[j];
        ad[i] = fmaxf(v, 0.f);
    }
    for (int c = 0; c < 2; ++c) {
        float v = db2[c];
        for (int j = 0; j < 2; ++j) v += dW2[c * 2 + j] * ad[j];
        scales[4 + c] = 1.f / (1.f + expf(-v));
    }
}

// ---------------------------------------------------------------------------
// build fusion inputs (scaled channel concat)
// ---------------------------------------------------------------------------
__global__ void cat_m_kernel(const float* __restrict__ c0, const float* __restrict__ c1,
                             const float* __restrict__ c2, const float* __restrict__ c3,
                             const float* __restrict__ scales, float* __restrict__ out) {
    int idx = blockIdx.x * blockDim.x + threadIdx.x;
    if (idx >= NM_ * 512) return;
    int i = idx >> 9;
    int k = idx & 511;
    int c = k >> 7;
    int j = k & 127;
    const float* p = (c == 0) ? c0 : (c == 1) ? c1 : (c == 2) ? c2 : c3;
    out[idx] = fmaxf(scales[c] * p[(size_t)i * D128 + j], 0.f);
}

__global__ void cat_d_kernel(const float* __restrict__ d1a, const float* __restrict__ d1b,
                             const float* __restrict__ d2a, const float* __restrict__ d2b,
                             const float* __restrict__ scales, float* __restrict__ out) {
    int idx = blockIdx.x * blockDim.x + threadIdx.x;
    if (idx >= ND_ * 256) return;
    int i = idx >> 8;
    int k = idx & 255;
    int c = k >> 7;
    int j = k & 127;
    const float* pa = c ? d1b : d1a;
    const float* pb = c ? d2b : d2a;
    out[idx] = fmaxf(scales[4 + c] * (pa[(size_t)i * D128 + j] + pb[(size_t)i * D128 + j]), 0.f);
}

// ---------------------------------------------------------------------------
extern "C" void kernel_launch(void* const* d_in, const int* in_sizes, int n_in,
                              void* d_out, int out_size, void* d_ws, size_t ws_size,
                              hipStream_t stream) {
    const float* mirna_x = (const float*)d_in[0];
    const float* drug_x  = (const float*)d_in[1];
    const float* m_fc1_W = (const float*)d_in[26];
    const float* m_fc1_b = (const float*)d_in[27];
    const float* m_fc2_W = (const float*)d_in[28];
    const float* m_fc2_b = (const float*)d_in[29];
    const float* d_fc1_W = (const float*)d_in[30];
    const float* d_fc1_b = (const float*)d_in[31];
    const float* d_fc2_W = (const float*)d_in[32];
    const float* d_fc2_b = (const float*)d_in[33];
    const float* m_fus_W1 = (const float*)d_in[34];
    const float* m_fus_b1 = (const float*)d_in[35];
    const float* m_fus_W2 = (const float*)d_in[36];
    const float* m_fus_b2 = (const float*)d_in[37];
    const float* d_fus_W1 = (const float*)d_in[38];
    const float* d_fus_b1 = (const float*)d_in[39];
    const float* d_fus_W2 = (const float*)d_in[40];
    const float* d_fus_b2 = (const float*)d_in[41];
    float* out = (float*)d_out;

    char* ws = (char*)d_ws;
    size_t off = 0;
    auto take = [&](size_t bytes) -> void* {
        void* p = ws + off;
        off += (bytes + 255) & ~(size_t)255;
        return p;
    };
    int*   ssrc   = (int*)take((size_t)ED_ * 4);
    float* snrm   = (float*)take((size_t)ED_ * 4);
    int*   pcnt   = (int*)take((size_t)NB * ND_ * 4);
    float* pdeg   = (float*)take((size_t)NB * ND_ * 4);
    int*   cum    = (int*)take((size_t)NB * ND_ * 4);
    int*   cnt    = (int*)take((size_t)ND_ * 4);
    int*   rowptr = (int*)take((size_t)(ND_ + 1) * 4);
    float* dinv   = (float*)take((size_t)ND_ * 4);
    float* hbuf   = (float*)take((size_t)ND_ * D128 * 4);
    float* m1a = (float*)take((size_t)NM_ * D128 * 4);
    float* m1b = (float*)take((size_t)NM_ * D128 * 4);
    float* m2a = (float*)take((size_t)NM_ * D128 * 4);
    float* m2b = (float*)take((size_t)NM_ * D128 * 4);
    float* d1a = (float*)take((size_t)ND_ * D128 * 4);
    float* d1b = (float*)take((size_t)ND_ * D128 * 4);
    float* d2a = (float*)take((size_t)ND_ * D128 * 4);
    float* d2b = (float*)take((size_t)ND_ * D128 * 4);
    float* partial = (float*)take((size_t)SPLITS * ND_ * D128 * 4);
    float* sums   = (float*)take(8 * 4);
    float* scales = (float*)take(8 * 4);
    float* catb   = (float*)take((size_t)ND_ * 256 * 4);
    float* fush1  = (float*)take((size_t)ND_ * 256 * 4);
    (void)ws_size; (void)in_sizes; (void)n_in; (void)out_size;

    auto run_view = [&](const int* edge, const float* w, const float* W1, const float* b1,
                        const float* W2, const float* b2, const float* x, float* out1,
                        float* out2, int n, int E) {
        hist_kernel<<<NB, 256, 0, stream>>>(edge, w, pcnt, pdeg, n, E);
        colred_kernel<<<(n + 255) / 256, 256, 0, stream>>>(pcnt, pdeg, cnt, dinv, n);
        scan_kernel<<<1, 256, 0, stream>>>(cnt, rowptr, n);
        cum_kernel<<<(n + 255) / 256, 256, 0, stream>>>(pcnt, rowptr, cum, n);
        fill2_kernel<<<NB, 256, 0, stream>>>(edge, w, dinv, cum, ssrc, snrm, n, E);
        // layer 1
        gemm_tn<false><<<dim3((n + 63) / 64, 2), 256, 0, stream>>>(x, W1, nullptr, hbuf, n, 128, 128);
        agg_kernel<<<dim3(n, SPLITS), 128, 0, stream>>>(ssrc, snrm, rowptr, hbuf, partial, n);
        reduce_bias_relu<<<(n * D128 + 255) / 256, 256, 0, stream>>>(partial, b1, out1, n);
        // layer 2
        gemm_tn<false><<<dim3((n + 63) / 64, 2), 256, 0, stream>>>(out1, W2, nullptr, hbuf, n, 128, 128);
        agg_kernel<<<dim3(n, SPLITS), 128, 0, stream>>>(ssrc, snrm, rowptr, hbuf, partial, n);
        reduce_bias_relu<<<(n * D128 + 255) / 256, 256, 0, stream>>>(partial, b2, out2, n);
    };

    run_view((const int*)d_in[2], (const float*)d_in[3], (const float*)d_in[4],
             (const float*)d_in[5], (const float*)d_in[6], (const float*)d_in[7], mirna_x,
             m1a, m1b, NM_, EM_);
    run_view((const int*)d_in[8], (const float*)d_in[9], (const float*)d_in[10],
             (const float*)d_in[11], (const float*)d_in[12], (const float*)d_in[13], mirna_x,
             m2a, m2b, NM_, EM_);
    run_view((const int*)d_in[14], (const float*)d_in[15], (const float*)d_in[16],
             (const float*)d_in[17], (const float*)d_in[18], (const float*)d_in[19], drug_x,
             d1a, d1b, ND_, ED_);
    run_view((const int*)d_in[20], (const float*)d_in[21], (const float*)d_in[22],
             (const float*)d_in[23], (const float*)d_in[24], (const float*)d_in[25], drug_x,
             d2a, d2b, ND_, ED_);

    // channel sums -> attention scales (one batched launch)
    hipMemsetAsync(sums, 0, 8 * 4, stream);
    SumArgs sa;
    sa.p[0] = m1a; sa.p[1] = m1b; sa.p[2] = m2a; sa.p[3] = m2b;
    sa.p[4] = d1a; sa.p[5] = d1b; sa.p[6] = d2a; sa.p[7] = d2b;
    sa.cnt[0] = sa.cnt[1] = sa.cnt[2] = sa.cnt[3] = NM_ * D128;
    sa.cnt[4] = sa.cnt[5] = sa.cnt[6] = sa.cnt[7] = ND_ * D128;
    sum8_kernel<<<dim3(16, 8), 256, 0, stream>>>(sa, sums);
    att_kernel<<<1, 64, 0, stream>>>(sums, m_fc1_W, m_fc1_b, m_fc2_W, m_fc2_b,
                                     d_fc1_W, d_fc1_b, d_fc2_W, d_fc2_b, scales);

    // miRNA fusion -> out[0 : NM)
    cat_m_kernel<<<(NM_ * 512 + 255) / 256, 256, 0, stream>>>(m1a, m1b, m2a, m2b, scales, catb);
    gemm_tn<true><<<dim3((NM_ + 63) / 64, 4), 256, 0, stream>>>(catb, m_fus_W1, m_fus_b1, fush1,
                                                                NM_, 256, 512);
    gemm_tn<true><<<dim3((NM_ + 63) / 64, 2), 256, 0, stream>>>(fush1, m_fus_W2, m_fus_b2, out,
                                                                NM_, 128, 256);
    // drug fusion -> out[NM : NM+ND)
    cat_d_kernel<<<(ND_ * 256 + 255) / 256, 256, 0, stream>>>(d1a, d1b, d2a, d2b, scales, catb);
    gemm_tn<true><<<dim3((ND_ + 63) / 64, 4), 256, 0, stream>>>(catb, d_fus_W1, d_fus_b1, fush1,
                                                                ND_, 256, 256);
    gemm_tn<true><<<dim3((ND_ + 63) / 64, 2), 256, 0, stream>>>(fush1, d_fus_W2, d_fus_b2,
                                                                out + (size_t)NM_ * D128, ND_, 128, 256);
}

// Round 3
// 316.588 us; speedup vs baseline: 3.5355x; 1.9163x over previous
//
#include <hip/hip_runtime.h>
#include <math.h>

#define D128 128
#define NM_ 1043
#define ND_ 2166
#define EM_ 300000
#define ED_ 600000
#define NBV 64
#define NMAX 2176
#define NTOT 6418           // 2*1043 + 2*2166
#define ETOT 1800000
#define SPLITS 2

struct ViewArgs {
    const int* edge[4];
    const float* w[4];
    int n[4], E[4];
    int cumn[5];
    int cumE[5];
    int rpo[4];
};

struct BiasArr { const float* b[4]; };

// ---------------------------------------------------------------------------
// CSR build (batched over 4 views)
// ---------------------------------------------------------------------------
__global__ __launch_bounds__(256) void hist_b(ViewArgs va, int* __restrict__ pcnt,
                                              float* __restrict__ pdeg) {
    __shared__ int lc[NMAX];
    __shared__ float ld[NMAX];
    const int view = blockIdx.x >> 6, vb = blockIdx.x & 63;
    const int n = va.n[view], E = va.E[view];
    const int* edge = va.edge[view];
    const float* w = va.w[view];
    for (int i = threadIdx.x; i < n; i += 256) { lc[i] = 0; ld[i] = 0.f; }
    __syncthreads();
    const int per = (E + NBV - 1) / NBV;
    const int b = vb * per, e = min(E, b + per);
    for (int i = b + threadIdx.x; i < e; i += 256) {
        int dst = edge[E + i];
        atomicAdd(&lc[dst], 1);
        atomicAdd(&ld[dst], w[i]);
    }
    __syncthreads();
    int* pc = pcnt + (size_t)NBV * va.cumn[view] + (size_t)vb * n;
    float* pd = pdeg + (size_t)NBV * va.cumn[view] + (size_t)vb * n;
    for (int i = threadIdx.x; i < n; i += 256) { pc[i] = lc[i]; pd[i] = ld[i]; }
}

__global__ void colred_b(ViewArgs va, const int* __restrict__ pcnt,
                         const float* __restrict__ pdeg, int* __restrict__ cnt,
                         float* __restrict__ dinv) {
    int i = blockIdx.x * 256 + threadIdx.x;
    if (i >= NTOT) return;
    int view = 0;
    while (view < 3 && i >= va.cumn[view + 1]) ++view;
    const int il = i - va.cumn[view], n = va.n[view];
    const int* pc = pcnt + (size_t)NBV * va.cumn[view];
    const float* pd = pdeg + (size_t)NBV * va.cumn[view];
    int c = 0;
    float dg = 0.f;
    for (int b = 0; b < NBV; ++b) {
        c += pc[(size_t)b * n + il];
        dg += pd[(size_t)b * n + il];
    }
    cnt[i] = c;
    dinv[i] = dg > 0.f ? 1.0f / sqrtf(dg) : 0.f;
}

__global__ void scan_b(ViewArgs va, const int* __restrict__ cnt, int* __restrict__ rowptr) {
    __shared__ int tmp[256];
    __shared__ int carry;
    const int view = blockIdx.x;
    const int n = va.n[view];
    const int* c = cnt + va.cumn[view];
    int* rp = rowptr + va.rpo[view];
    const int tid = threadIdx.x;
    if (tid == 0) { carry = 0; rp[0] = 0; }
    __syncthreads();
    for (int base = 0; base < n; base += 256) {
        int i = base + tid;
        int v = (i < n) ? c[i] : 0;
        tmp[tid] = v;
        __syncthreads();
        for (int off = 1; off < 256; off <<= 1) {
            int t = (tid >= off) ? tmp[tid - off] : 0;
            __syncthreads();
            tmp[tid] += t;
            __syncthreads();
        }
        if (i < n) rp[i + 1] = carry + tmp[tid];
        __syncthreads();
        if (tid == 255) carry += tmp[255];
        __syncthreads();
    }
}

__global__ void cum_b(ViewArgs va, const int* __restrict__ pcnt,
                      const int* __restrict__ rowptr, int* __restrict__ cum) {
    int i = blockIdx.x * 256 + threadIdx.x;
    if (i >= NTOT) return;
    int view = 0;
    while (view < 3 && i >= va.cumn[view + 1]) ++view;
    const int il = i - va.cumn[view], n = va.n[view];
    const int* pc = pcnt + (size_t)NBV * va.cumn[view];
    int* cm = cum + (size_t)NBV * va.cumn[view];
    int run = rowptr[va.rpo[view] + il];
    for (int b = 0; b < NBV; ++b) {
        cm[(size_t)b * n + il] = run;
        run += pc[(size_t)b * n + il];
    }
}

__global__ __launch_bounds__(256) void fill2_b(ViewArgs va, const float* __restrict__ dinv,
                                               const int* __restrict__ cum,
                                               int* __restrict__ ssrc,
                                               float* __restrict__ snrm) {
    __shared__ int lc[NMAX];
    const int view = blockIdx.x >> 6, vb = blockIdx.x & 63;
    const int n = va.n[view], E = va.E[view];
    const int* edge = va.edge[view];
    const float* w = va.w[view];
    const int* cm = cum + (size_t)NBV * va.cumn[view] + (size_t)vb * n;
    const float* dv = dinv + va.cumn[view];
    int* ss = ssrc + va.cumE[view];
    float* sn = snrm + va.cumE[view];
    for (int i = threadIdx.x; i < n; i += 256) lc[i] = cm[i];
    __syncthreads();
    const int per = (E + NBV - 1) / NBV;
    const int b = vb * per, e = min(E, b + per);
    for (int i = b + threadIdx.x; i < e; i += 256) {
        int src = edge[i];
        int dst = edge[E + i];
        int pos = atomicAdd(&lc[dst], 1);
        ss[pos] = src;
        sn[pos] = dv[src] * w[i] * dv[dst];
    }
}

// ---------------------------------------------------------------------------
// batched edge aggregation
// ---------------------------------------------------------------------------
__global__ __launch_bounds__(128) void agg_b(ViewArgs va, const int* __restrict__ ssrc,
                                             const float* __restrict__ snrm,
                                             const int* __restrict__ rowptr,
                                             const float* __restrict__ h,
                                             float* __restrict__ partial) {
    const int nf = blockIdx.x;
    int view = 0;
    while (view < 3 && nf >= va.cumn[view + 1]) ++view;
    const int ln = nf - va.cumn[view];
    const int* rp = rowptr + va.rpo[view];
    const int beg = rp[ln], end = rp[ln + 1];
    const int eo = va.cumE[view];
    const float* hb = h + (size_t)va.cumn[view] * D128;
    const int tid = threadIdx.x;
    const int sp = blockIdx.y;
    const int len = end - beg;
    int b = beg + (len * sp) / SPLITS;
    int e = beg + (len * (sp + 1)) / SPLITS;
    float a0 = 0.f, a1 = 0.f, a2 = 0.f, a3 = 0.f;
    int i = b;
    for (; i + 4 <= e; i += 4) {
        int s0 = ssrc[eo + i], s1 = ssrc[eo + i + 1], s2 = ssrc[eo + i + 2], s3 = ssrc[eo + i + 3];
        float w0 = snrm[eo + i], w1 = snrm[eo + i + 1], w2 = snrm[eo + i + 2], w3 = snrm[eo + i + 3];
        a0 = fmaf(w0, hb[(size_t)s0 * D128 + tid], a0);
        a1 = fmaf(w1, hb[(size_t)s1 * D128 + tid], a1);
        a2 = fmaf(w2, hb[(size_t)s2 * D128 + tid], a2);
        a3 = fmaf(w3, hb[(size_t)s3 * D128 + tid], a3);
    }
    for (; i < e; ++i) a0 = fmaf(snrm[eo + i], hb[(size_t)ssrc[eo + i] * D128 + tid], a0);
    partial[((size_t)sp * NTOT + nf) * D128 + tid] = (a0 + a1) + (a2 + a3);
}

__global__ void reduce_b(ViewArgs va, const float* __restrict__ partial, BiasArr ba,
                         float* __restrict__ outbuf) {
    int idx = blockIdx.x * 256 + threadIdx.x;
    if (idx >= NTOT * D128) return;
    float v = partial[idx] + partial[(size_t)NTOT * D128 + idx];
    int nf = idx >> 7;
    int view = 0;
    while (view < 3 && nf >= va.cumn[view + 1]) ++view;
    outbuf[idx] = fmaxf(v + ba.b[view][idx & 127], 0.f);
}

// ---------------------------------------------------------------------------
// unified multi-segment GEMM: C[M,N] = A[M,K] @ W[N,K]^T (+bias, relu)
// 32x128 tile, K-chunk 64, XOR-swizzled W in LDS, 4x4 microtile.
// ---------------------------------------------------------------------------
struct GSeg {
    const float* A;
    const float* W;
    const float* bias;
    float* C;
    int M, N, K, rowblks, blk0, relu;
};
struct GArgs { GSeg s[4]; int nseg; };

__global__ __launch_bounds__(256) void gemm_b(GArgs ga) {
    __shared__ float xs[32 * 64];
    __shared__ float wsm[128 * 64];
    int si = 0;
    while (si + 1 < ga.nseg && (int)blockIdx.x >= ga.s[si + 1].blk0) ++si;
    const GSeg S = ga.s[si];
    const int lb = blockIdx.x - S.blk0;
    const int rb = lb % S.rowblks, cb = lb / S.rowblks;
    const int row0 = rb * 32, col0 = cb * 128;
    const int tid = threadIdx.x;
    const int r0 = (tid >> 5) << 2;    // 0,4,...,28
    const int c0 = tid & 31;           // +32j, j=0..3
    const int csw = (c0 & 7) << 2;
    float acc[4][4] = {};
    for (int kc = 0; kc < S.K; kc += 64) {
#pragma unroll
        for (int it = 0; it < 2; ++it) {
            int idx = tid + it * 256;
            int r = idx >> 4, k4 = (idx & 15) << 2;
            int gr = row0 + r;
            if (gr > S.M - 1) gr = S.M - 1;
            *(float4*)(xs + r * 64 + k4) =
                *(const float4*)(S.A + (size_t)gr * S.K + kc + k4);
        }
#pragma unroll
        for (int it = 0; it < 8; ++it) {
            int idx = tid + it * 256;
            int c = idx >> 4, k4 = (idx & 15) << 2;
            *(float4*)(wsm + c * 64 + (k4 ^ ((c & 7) << 2))) =
                *(const float4*)(S.W + (size_t)(col0 + c) * S.K + kc + k4);
        }
        __syncthreads();
#pragma unroll
        for (int k4 = 0; k4 < 64; k4 += 4) {
            float4 a0 = *(const float4*)(xs + (r0 + 0) * 64 + k4);
            float4 a1 = *(const float4*)(xs + (r0 + 1) * 64 + k4);
            float4 a2 = *(const float4*)(xs + (r0 + 2) * 64 + k4);
            float4 a3 = *(const float4*)(xs + (r0 + 3) * 64 + k4);
            const int sk = k4 ^ csw;
            float4 w0 = *(const float4*)(wsm + (c0 + 0) * 64 + sk);
            float4 w1 = *(const float4*)(wsm + (c0 + 32) * 64 + sk);
            float4 w2 = *(const float4*)(wsm + (c0 + 64) * 64 + sk);
            float4 w3 = *(const float4*)(wsm + (c0 + 96) * 64 + sk);
#define FMA4(i, av)                                                   \
            acc[i][0] = fmaf(av.x, w0.x, acc[i][0]); acc[i][0] = fmaf(av.y, w0.y, acc[i][0]); \
            acc[i][0] = fmaf(av.z, w0.z, acc[i][0]); acc[i][0] = fmaf(av.w, w0.w, acc[i][0]); \
            acc[i][1] = fmaf(av.x, w1.x, acc[i][1]); acc[i][1] = fmaf(av.y, w1.y, acc[i][1]); \
            acc[i][1] = fmaf(av.z, w1.z, acc[i][1]); acc[i][1] = fmaf(av.w, w1.w, acc[i][1]); \
            acc[i][2] = fmaf(av.x, w2.x, acc[i][2]); acc[i][2] = fmaf(av.y, w2.y, acc[i][2]); \
            acc[i][2] = fmaf(av.z, w2.z, acc[i][2]); acc[i][2] = fmaf(av.w, w2.w, acc[i][2]); \
            acc[i][3] = fmaf(av.x, w3.x, acc[i][3]); acc[i][3] = fmaf(av.y, w3.y, acc[i][3]); \
            acc[i][3] = fmaf(av.z, w3.z, acc[i][3]); acc[i][3] = fmaf(av.w, w3.w, acc[i][3]);
            FMA4(0, a0) FMA4(1, a1) FMA4(2, a2) FMA4(3, a3)
#undef FMA4
        }
        __syncthreads();
    }
#pragma unroll
    for (int i = 0; i < 4; ++i) {
        int gr = row0 + r0 + i;
        if (gr < S.M) {
#pragma unroll
            for (int j = 0; j < 4; ++j) {
                int gc = col0 + c0 + 32 * j;
                float v = acc[i][j];
                if (S.bias) v += S.bias[gc];
                if (S.relu) v = fmaxf(v, 0.f);
                S.C[(size_t)gr * S.N + gc] = v;
            }
        }
    }
}

// ---------------------------------------------------------------------------
// channel sums + attention scales + concat
// ---------------------------------------------------------------------------
struct SumArgs {
    const float* p[8];
    int cnt[8];
};

__global__ __launch_bounds__(256) void sum8_kernel(SumArgs args, float* __restrict__ sums) {
    __shared__ float red[256];
    const int ch = blockIdx.y;
    const float* x = args.p[ch];
    const int count = args.cnt[ch];
    float s = 0.f;
    for (int i = blockIdx.x * 256 + threadIdx.x; i < count; i += gridDim.x * 256) s += x[i];
    red[threadIdx.x] = s;
    __syncthreads();
    for (int off = 128; off > 0; off >>= 1) {
        if (threadIdx.x < off) red[threadIdx.x] += red[threadIdx.x + off];
        __syncthreads();
    }
    if (threadIdx.x == 0) atomicAdd(&sums[ch], red[0]);
}

__global__ void att_kernel(const float* __restrict__ sums,
                           const float* __restrict__ mW1, const float* __restrict__ mb1,
                           const float* __restrict__ mW2, const float* __restrict__ mb2,
                           const float* __restrict__ dW1, const float* __restrict__ db1,
                           const float* __restrict__ dW2, const float* __restrict__ db2,
                           float* __restrict__ scales) {
    if (threadIdx.x != 0 || blockIdx.x != 0) return;
    float mean[4], a[4];
    const float invM = 1.0f / (128.f * (float)NM_);
    for (int c = 0; c < 4; ++c) mean[c] = sums[c] * invM;
    for (int i = 0; i < 4; ++i) {
        float v = mb1[i];
        for (int j = 0; j < 4; ++j) v += mW1[i * 4 + j] * mean[j];
        a[i] = fmaxf(v, 0.f);
    }
    for (int c = 0; c < 4; ++c) {
        float v = mb2[c];
        for (int j = 0; j < 4; ++j) v += mW2[c * 4 + j] * a[j];
        scales[c] = 1.f / (1.f + expf(-v));
    }
    const float invD = 1.0f / (128.f * (float)ND_);
    float md[2] = {(sums[4] + sums[6]) * invD, (sums[5] + sums[7]) * invD};
    float ad[2];
    for (int i = 0; i < 2; ++i) {
        float v = db1[i];
        for (int j = 0; j < 2; ++j) v += dW1[i * 2 + j] * md[j];
        ad[i] = fmaxf(v, 0.f);
    }
    for (int c = 0; c < 2; ++c) {
        float v = db2[c];
        for (int j = 0; j < 2; ++j) v += dW2[c * 2 + j] * ad[j];
        scales[4 + c] = 1.f / (1.f + expf(-v));
    }
}

__global__ void cat_m_kernel(const float* __restrict__ c0, const float* __restrict__ c1,
                             const float* __restrict__ c2, const float* __restrict__ c3,
                             const float* __restrict__ scales, float* __restrict__ out) {
    int idx = blockIdx.x * blockDim.x + threadIdx.x;
    if (idx >= NM_ * 512) return;
    int i = idx >> 9;
    int k = idx & 511;
    int c = k >> 7;
    int j = k & 127;
    const float* p = (c == 0) ? c0 : (c == 1) ? c1 : (c == 2) ? c2 : c3;
    out[idx] = fmaxf(scales[c] * p[(size_t)i * D128 + j], 0.f);
}

__global__ void cat_d_kernel(const float* __restrict__ l1, const float* __restrict__ l2,
                             const float* __restrict__ scales, float* __restrict__ out) {
    int idx = blockIdx.x * blockDim.x + threadIdx.x;
    if (idx >= ND_ * 256) return;
    int i = idx >> 8;
    int k = idx & 255;
    int c = k >> 7;
    int j = k & 127;
    const float* pa = (c ? l2 : l1) + (size_t)2086 * D128;
    const float* pb = (c ? l2 : l1) + (size_t)4252 * D128;
    out[idx] = fmaxf(scales[4 + c] * (pa[(size_t)i * D128 + j] + pb[(size_t)i * D128 + j]), 0.f);
}

// ---------------------------------------------------------------------------
extern "C" void kernel_launch(void* const* d_in, const int* in_sizes, int n_in,
                              void* d_out, int out_size, void* d_ws, size_t ws_size,
                              hipStream_t stream) {
    const float* mirna_x = (const float*)d_in[0];
    const float* drug_x  = (const float*)d_in[1];
    float* out = (float*)d_out;
    (void)in_sizes; (void)n_in; (void)out_size; (void)ws_size;

    char* ws = (char*)d_ws;
    auto AL = [](size_t x) { return (x + 255) & ~(size_t)255; };
    size_t o = 0;
    int* ssrc = (int*)(ws + o);      o += AL((size_t)ETOT * 4);
    float* snrm = (float*)(ws + o);  o += AL((size_t)ETOT * 4);
    int* cnt = (int*)(ws + o);       o += AL((size_t)NTOT * 4);
    int* rowptr = (int*)(ws + o);    o += AL((size_t)(NTOT + 4) * 4);
    float* dinv = (float*)(ws + o);  o += AL((size_t)NTOT * 4);
    float* sums = (float*)(ws + o);  o += 256;
    float* scales = (float*)(ws + o); o += 256;
    // overlaid region R
    const size_t R = o;
    const size_t pcsz = AL((size_t)NBV * NTOT * 4);
    int*   pcnt = (int*)(ws + R);
    float* pdeg = (float*)(ws + R + pcsz);
    int*   cum  = (int*)(ws + R + 2 * pcsz);
    const size_t hsz = AL((size_t)NTOT * D128 * 4);
    float* hbuf = (float*)(ws + R);
    float* partial = (float*)(ws + R + hsz);
    const size_t cmsz = AL((size_t)NM_ * 512 * 4);
    const size_t cdsz = AL((size_t)ND_ * 256 * 4);
    float* catb_m = (float*)(ws + R);
    float* catb_d = (float*)(ws + R + cmsz);
    float* fush1_m = (float*)(ws + R + cmsz + cdsz);
    float* fush1_d = fush1_m + (size_t)NM_ * 256;
    size_t rsz = hsz + AL((size_t)SPLITS * NTOT * D128 * 4);   // largest phase
    o = R + rsz;
    float* l1out = (float*)(ws + o); o += hsz;
    float* l2out = (float*)(ws + o); o += hsz;

    ViewArgs va;
    const int vb_in[4] = {2, 8, 14, 20};
    int nn[4] = {NM_, NM_, ND_, ND_};
    int ee[4] = {EM_, EM_, ED_, ED_};
    int cn = 0, ce = 0;
    for (int v = 0; v < 4; ++v) {
        va.edge[v] = (const int*)d_in[vb_in[v]];
        va.w[v] = (const float*)d_in[vb_in[v] + 1];
        va.n[v] = nn[v];
        va.E[v] = ee[v];
        va.cumn[v] = cn;
        va.cumE[v] = ce;
        va.rpo[v] = cn + v;
        cn += nn[v];
        ce += ee[v];
    }
    va.cumn[4] = cn;
    va.cumE[4] = ce;

    // ---- CSR build (all views) ----
    hist_b<<<256, 256, 0, stream>>>(va, pcnt, pdeg);
    colred_b<<<(NTOT + 255) / 256, 256, 0, stream>>>(va, pcnt, pdeg, cnt, dinv);
    scan_b<<<4, 256, 0, stream>>>(va, cnt, rowptr);
    cum_b<<<(NTOT + 255) / 256, 256, 0, stream>>>(va, pcnt, rowptr, cum);
    fill2_b<<<256, 256, 0, stream>>>(va, dinv, cum, ssrc, snrm);

    // ---- layer GEMMs + aggregation ----
    auto feat_gemm = [&](int layer, const float* l1src) {
        GArgs ga;
        ga.nseg = 4;
        int blk = 0;
        for (int v = 0; v < 4; ++v) {
            GSeg& S = ga.s[v];
            S.A = (layer == 1) ? ((v < 2) ? mirna_x : drug_x)
                               : l1src + (size_t)va.cumn[v] * D128;
            S.W = (const float*)d_in[vb_in[v] + (layer == 1 ? 2 : 4)];
            S.bias = nullptr;
            S.C = hbuf + (size_t)va.cumn[v] * D128;
            S.M = va.n[v]; S.N = 128; S.K = 128;
            S.rowblks = (va.n[v] + 31) / 32;
            S.blk0 = blk; S.relu = 0;
            blk += S.rowblks;
        }
        gemm_b<<<blk, 256, 0, stream>>>(ga);
    };
    BiasArr b1, b2;
    for (int v = 0; v < 4; ++v) {
        b1.b[v] = (const float*)d_in[vb_in[v] + 3];
        b2.b[v] = (const float*)d_in[vb_in[v] + 5];
    }

    feat_gemm(1, nullptr);
    agg_b<<<dim3(NTOT, SPLITS), 128, 0, stream>>>(va, ssrc, snrm, rowptr, hbuf, partial);
    reduce_b<<<(NTOT * D128 + 255) / 256, 256, 0, stream>>>(va, partial, b1, l1out);
    feat_gemm(2, l1out);
    agg_b<<<dim3(NTOT, SPLITS), 128, 0, stream>>>(va, ssrc, snrm, rowptr, hbuf, partial);
    reduce_b<<<(NTOT * D128 + 255) / 256, 256, 0, stream>>>(va, partial, b2, l2out);

    // ---- channel sums -> attention scales ----
    hipMemsetAsync(sums, 0, 8 * 4, stream);
    SumArgs sa;
    sa.p[0] = l1out;                      sa.p[1] = l2out;
    sa.p[2] = l1out + (size_t)1043 * 128; sa.p[3] = l2out + (size_t)1043 * 128;
    sa.p[4] = l1out + (size_t)2086 * 128; sa.p[5] = l2out + (size_t)2086 * 128;
    sa.p[6] = l1out + (size_t)4252 * 128; sa.p[7] = l2out + (size_t)4252 * 128;
    sa.cnt[0] = sa.cnt[1] = sa.cnt[2] = sa.cnt[3] = NM_ * D128;
    sa.cnt[4] = sa.cnt[5] = sa.cnt[6] = sa.cnt[7] = ND_ * D128;
    sum8_kernel<<<dim3(16, 8), 256, 0, stream>>>(sa, sums);
    att_kernel<<<1, 64, 0, stream>>>(sums,
        (const float*)d_in[26], (const float*)d_in[27], (const float*)d_in[28], (const float*)d_in[29],
        (const float*)d_in[30], (const float*)d_in[31], (const float*)d_in[32], (const float*)d_in[33],
        scales);

    // ---- concat (scaled) ----
    cat_m_kernel<<<(NM_ * 512 + 255) / 256, 256, 0, stream>>>(
        l1out, l2out, l1out + (size_t)1043 * 128, l2out + (size_t)1043 * 128, scales, catb_m);
    cat_d_kernel<<<(ND_ * 256 + 255) / 256, 256, 0, stream>>>(l1out, l2out, scales, catb_d);

    // ---- fusion GEMMs (m + d batched) ----
    {
        GArgs ga;
        ga.nseg = 2;
        ga.s[0] = {catb_m, (const float*)d_in[34], (const float*)d_in[35], fush1_m,
                   NM_, 256, 512, 33, 0, 1};
        ga.s[1] = {catb_d, (const float*)d_in[38], (const float*)d_in[39], fush1_d,
                   ND_, 256, 256, 68, 66, 1};
        gemm_b<<<66 + 136, 256, 0, stream>>>(ga);
    }
    {
        GArgs ga;
        ga.nseg = 2;
        ga.s[0] = {fush1_m, (const float*)d_in[36], (const float*)d_in[37], out,
                   NM_, 128, 256, 33, 0, 1};
        ga.s[1] = {fush1_d, (const float*)d_in[40], (const float*)d_in[41],
                   out + (size_t)NM_ * D128, ND_, 128, 256, 68, 33, 1};
        gemm_b<<<33 + 68, 256, 0, stream>>>(ga);
    }
}